// Round 7
// baseline (66.884 us; speedup 1.0000x reference)
//
#include <hip/hip_runtime.h>
#include <hip/hip_bf16.h>

#define BB 4
#define SS 1024
#define NSD (BB*SS*64)

typedef __attribute__((ext_vector_type(4))) float f32x4;
typedef __attribute__((ext_vector_type(8))) short bf16x8;

__device__ __forceinline__ float fast_exp2(float x) { return __builtin_amdgcn_exp2f(x); }
__device__ __forceinline__ float fast_rcp(float x)  { return __builtin_amdgcn_rcpf(x); }

__device__ __forceinline__ unsigned short f2bf(float f) {
    unsigned int u = __builtin_bit_cast(unsigned int, f);
    u += 0x7fffu + ((u >> 16) & 1u);
    return (unsigned short)(u >> 16);
}
__device__ __forceinline__ float bf2f(unsigned short u) {
    unsigned int v = (unsigned int)u << 16;
    return __builtin_bit_cast(float, v);
}

// sum of 4 sigmoids 1/(1+eq_d*ek_d) with one reciprocal
__device__ __forceinline__ float sig4(const f32x4 eq, const f32x4 ek) {
    float A = __builtin_fmaf(eq[0], ek[0], 1.0f);
    float B = __builtin_fmaf(eq[1], ek[1], 1.0f);
    float C = __builtin_fmaf(eq[2], ek[2], 1.0f);
    float D = __builtin_fmaf(eq[3], ek[3], 1.0f);
    float AB = A*B, CD = C*D;
    float num = __builtin_fmaf(A+B, CD, (C+D)*AB);
    return num * fast_rcp(AB*CD);
}

// ---------------------------------------------------------------------------
// K1: projections + hi/lo bf16 splits (unchanged from round 6).
// ---------------------------------------------------------------------------
__global__ __launch_bounds__(256) void k_proj(
    const float* __restrict__ x, const float* __restrict__ Wq,
    const float* __restrict__ Wk, const float* __restrict__ bkv,
    const float* __restrict__ Wv,
    unsigned short* __restrict__ qh, unsigned short* __restrict__ ql,
    unsigned short* __restrict__ kh, unsigned short* __restrict__ kl,
    unsigned short* __restrict__ xh, unsigned short* __restrict__ xlo,
    float* __restrict__ exf,
    unsigned short* __restrict__ xT, unsigned short* __restrict__ vT)
{
    __shared__ float xsh[4*68];
    const int t = threadIdx.x;
    const int r = t & 3, cc = t >> 2;
    const int row0 = blockIdx.x * 4;
    if (t < 64) {
        const int rr = t >> 4, seg = (t & 15) * 4;
        *(f32x4*)(xsh + rr*68 + seg) =
            *(const f32x4*)(x + (size_t)(row0 + rr)*64 + seg);
    }
    __syncthreads();

    const float* wqp = Wq + cc*64;
    const float* wkp = Wk + cc*64;
    const float* wvp = Wv + cc*64;
    float aq = 0.f, ak = 0.f, av = 0.f;
    #pragma unroll 4
    for (int e0 = 0; e0 < 64; e0 += 4) {
        f32x4 xv = *(const f32x4*)(xsh + r*68 + e0);
        f32x4 q4 = *(const f32x4*)(wqp + e0);
        f32x4 k4 = *(const f32x4*)(wkp + e0);
        f32x4 v4 = *(const f32x4*)(wvp + e0);
        #pragma unroll
        for (int u = 0; u < 4; ++u) {
            aq = __builtin_fmaf(xv[u], q4[u], aq);
            ak = __builtin_fmaf(xv[u], k4[u], ak);
            av = __builtin_fmaf(xv[u], v4[u], av);
        }
    }
    const int row = row0 + r;
    const int b = row >> 10, srow = row & 1023;
    const float C2 = 2.8853900817779268f;   // 2*log2(e)
    ak += bkv[cc];
    const size_t idx = (size_t)row*64 + cc;
    unsigned short h;
    h = f2bf(aq); qh[idx] = h; ql[idx] = f2bf(aq - bf2f(h));
    h = f2bf(ak); kh[idx] = h; kl[idx] = f2bf(ak - bf2f(h));
    const float xv_ = xsh[r*68 + cc];
    h = f2bf(xv_); xh[idx] = h; xlo[idx] = f2bf(xv_ - bf2f(h));
    exf[idx] = fast_exp2(C2 * xv_);
    xT[((size_t)b*64 + cc)*1024 + srow] = h;
    vT[((size_t)b*64 + cc)*1024 + srow] = f2bf(av);
}

// ---------------------------------------------------------------------------
// K2: fused scores+softmax+PV.
//  bx <  512 : branch 3, 4 INDEPENDENT waves/block, zero LDS, zero barriers.
//    wave w=bx*4+wv -> (s8=w&7, b=(w>>3)&3, qt=63-(w>>5)); 16-row q-tile,
//    32-k steps c = s8, s8+8, ... Lane computes score row lane&15, cols
//    (lane>>4)*8+j == MFMA A-frag layout; eq/ek read direct from global exf;
//    P stays in registers; V B-frags direct from xT. Slots 4+s8.
//  bx >= 512 : branches 1,2 (split-bf16 MFMA scores), as round 6. Slots 0..3.
// ---------------------------------------------------------------------------
__global__ __launch_bounds__(256) void k_fused(
    const unsigned short* __restrict__ xh, const unsigned short* __restrict__ xlo,
    const unsigned short* __restrict__ qh, const unsigned short* __restrict__ ql,
    const unsigned short* __restrict__ kh, const unsigned short* __restrict__ kl,
    const float* __restrict__ exf,
    const unsigned short* __restrict__ xT, const unsigned short* __restrict__ vT,
    const float* __restrict__ attn_scale,
    float* __restrict__ po, float* __restrict__ lb)
{
    __shared__ unsigned short Pl[16*72];
    __shared__ float lpart[4][16];

    const int t = threadIdx.x;
    const int bx = blockIdx.x;
    const int lane = t & 63, wv = t >> 6;
    const int l15 = lane & 15, g = lane >> 4;
    const float LOG2E = 1.4426950408889634f;

    if (bx < 512) {
        // ================= branch 3: wave-independent, LDS-free =============
        const int w = bx*4 + wv;
        const int s8 = w & 7, b = (w >> 3) & 3;
        const int qt = 63 - (w >> 5);
        const int q0 = qt * 16;
        const int q = q0 + l15;
        const int nsteps = (qt >> 1) + 1;          // 32-wide k-steps

        const float* eqp = exf + ((size_t)b*SS + q0 + l15)*64;
        const float* ekb = exf + (size_t)b*SS*64;
        const unsigned short* vb = xT + (size_t)b*64*1024;

        f32x4 a0 = {0,0,0,0}, a1 = {0,0,0,0}, a2 = {0,0,0,0}, a3 = {0,0,0,0};
        float lsum = 0.f;

        for (int c = s8; c < nsteps; c += 8) {
            const int kc = c * 32;
            const int kb0 = kc + g*8;
            const float* ekp = ekb + (size_t)kb0*64;
            float ar[8] = {0.f,0.f,0.f,0.f,0.f,0.f,0.f,0.f};
            #pragma unroll 4
            for (int d0 = 0; d0 < 64; d0 += 4) {
                f32x4 eqv = *(const f32x4*)(eqp + d0);
                #pragma unroll
                for (int jj = 0; jj < 8; ++jj) {
                    f32x4 ekv = *(const f32x4*)(ekp + (size_t)jj*64 + d0);
                    ar[jj] += sig4(eqv, ekv);
                }
            }
            // p = e^{s3-32}, s3 = 64 - 2*ar  ->  exp2(fma(ar,-2log2e, 32log2e))
            bf16x8 af;
            #pragma unroll
            for (int jj = 0; jj < 8; ++jj) {
                float e = (kb0 + jj <= q)
                    ? fast_exp2(__builtin_fmaf(ar[jj], -2.8853900817779268f,
                                               46.166241308446475f))
                    : 0.f;
                lsum += e;
                af[jj] = (short)f2bf(e);
            }
            bf16x8 b0 = *(const bf16x8*)(vb + (size_t)( 0 + l15)*1024 + kb0);
            bf16x8 b1 = *(const bf16x8*)(vb + (size_t)(16 + l15)*1024 + kb0);
            bf16x8 b2 = *(const bf16x8*)(vb + (size_t)(32 + l15)*1024 + kb0);
            bf16x8 b3 = *(const bf16x8*)(vb + (size_t)(48 + l15)*1024 + kb0);
            a0 = __builtin_amdgcn_mfma_f32_16x16x32_bf16(af, b0, a0, 0, 0, 0);
            a1 = __builtin_amdgcn_mfma_f32_16x16x32_bf16(af, b1, a1, 0, 0, 0);
            a2 = __builtin_amdgcn_mfma_f32_16x16x32_bf16(af, b2, a2, 0, 0, 0);
            a3 = __builtin_amdgcn_mfma_f32_16x16x32_bf16(af, b3, a3, 0, 0, 0);
        }

        lsum += __shfl_xor(lsum, 16, 64);
        lsum += __shfl_xor(lsum, 32, 64);

        const size_t slot = 4 + s8;
        if (lane < 16)
            lb[slot*(size_t)(BB*SS) + (size_t)b*SS + q0 + lane] = lsum;
        float* pob = po + slot*(size_t)NSD + ((size_t)b*SS + q0)*64;
        #pragma unroll
        for (int i = 0; i < 4; ++i) {
            const int rr = g*4 + i;
            pob[(size_t)rr*64 +  0 + l15] = a0[i];
            pob[(size_t)rr*64 + 16 + l15] = a1[i];
            pob[(size_t)rr*64 + 32 + l15] = a2[i];
            pob[(size_t)rr*64 + 48 + l15] = a3[i];
        }
    } else {
        // ================= branches 1,2 (round-6 verified path) =============
        const int y = bx - 512;
        const int split = y & 1, b = (y >> 1) & 3;
        const int qt = 63 - ((y >> 3) & 63);
        const int br = (y >> 9) & 1;
        const int q0 = qt * 16;
        const int nc = (qt >> 2) + 1;

        const unsigned short* Ah_p = (br ? qh : xh) + ((size_t)b*SS + q0)*64;
        const unsigned short* Al_p = (br ? ql : xlo) + ((size_t)b*SS + q0)*64;
        const unsigned short* Bh_p = (br ? kh : xh) + (size_t)b*SS*64;
        const unsigned short* Bl_p = (br ? kl : xlo) + (size_t)b*SS*64;
        const unsigned short* Vb   = (br ? vT : xT) + (size_t)b*64*1024;

        const int ko = g * 8;
        bf16x8 Ah0 = *(const bf16x8*)(Ah_p + (size_t)l15*64 + ko);
        bf16x8 Ah1 = *(const bf16x8*)(Ah_p + (size_t)l15*64 + 32 + ko);
        bf16x8 Al0 = *(const bf16x8*)(Al_p + (size_t)l15*64 + ko);
        bf16x8 Al1 = *(const bf16x8*)(Al_p + (size_t)l15*64 + 32 + ko);

        const float pscale = br ? (0.125f * attn_scale[0] * LOG2E) : LOG2E;
        const float pshift = br ? 0.f : (-64.f * LOG2E);

        f32x4 lacc = {0,0,0,0};
        f32x4 oacc = {0,0,0,0};

        for (int c = split; c < nc; c += 2) {
            const int kc = c * 64;
            const int krow = kc + wv*16 + l15;
            bf16x8 Bh0 = *(const bf16x8*)(Bh_p + (size_t)krow*64 + ko);
            bf16x8 Bh1 = *(const bf16x8*)(Bh_p + (size_t)krow*64 + 32 + ko);
            bf16x8 Bl0 = *(const bf16x8*)(Bl_p + (size_t)krow*64 + ko);
            bf16x8 Bl1 = *(const bf16x8*)(Bl_p + (size_t)krow*64 + 32 + ko);
            f32x4 s = {0,0,0,0};
            s = __builtin_amdgcn_mfma_f32_16x16x32_bf16(Ah0, Bh0, s, 0, 0, 0);
            s = __builtin_amdgcn_mfma_f32_16x16x32_bf16(Ah1, Bh1, s, 0, 0, 0);
            s = __builtin_amdgcn_mfma_f32_16x16x32_bf16(Ah0, Bl0, s, 0, 0, 0);
            s = __builtin_amdgcn_mfma_f32_16x16x32_bf16(Ah1, Bl1, s, 0, 0, 0);
            s = __builtin_amdgcn_mfma_f32_16x16x32_bf16(Al0, Bh0, s, 0, 0, 0);
            s = __builtin_amdgcn_mfma_f32_16x16x32_bf16(Al1, Bh1, s, 0, 0, 0);
            const int kg = kc + wv*16 + l15;
            #pragma unroll
            for (int i = 0; i < 4; ++i) {
                const int q = q0 + g*4 + i;
                float e = (kg <= q) ? fast_exp2(__builtin_fmaf(s[i], pscale, pshift)) : 0.f;
                lacc[i] += e;
                Pl[(g*4+i)*72 + wv*16 + l15] = f2bf(e);
            }
            __syncthreads();
            #pragma unroll
            for (int ks = 0; ks < 2; ++ks) {
                bf16x8 af = *(const bf16x8*)(Pl + l15*72 + ks*32 + g*8);
                bf16x8 bf_ = *(const bf16x8*)(Vb + (size_t)(wv*16 + l15)*1024 + kc + ks*32 + g*8);
                oacc = __builtin_amdgcn_mfma_f32_16x16x32_bf16(af, bf_, oacc, 0, 0, 0);
            }
            __syncthreads();
        }
        #pragma unroll
        for (int off = 8; off >= 1; off >>= 1) {
            lacc[0] += __shfl_xor(lacc[0], off, 64);
            lacc[1] += __shfl_xor(lacc[1], off, 64);
            lacc[2] += __shfl_xor(lacc[2], off, 64);
            lacc[3] += __shfl_xor(lacc[3], off, 64);
        }
        if (l15 == 0) {
            #pragma unroll
            for (int i = 0; i < 4; ++i) lpart[wv][g*4 + i] = lacc[i];
        }
        __syncthreads();
        const size_t slot = (size_t)(br*2 + split);
        if (t < 16) {
            float l = lpart[0][t] + lpart[1][t] + lpart[2][t] + lpart[3][t];
            lb[slot*((size_t)BB*SS) + (size_t)b*SS + q0 + t] = l;
        }
        float* pob = po + slot*((size_t)NSD) + ((size_t)b*SS + q0)*64;
        #pragma unroll
        for (int i = 0; i < 4; ++i)
            pob[(size_t)(g*4 + i)*64 + wv*16 + l15] = oacc[i];
    }
}

// ---------------------------------------------------------------------------
// K3: out = w0*(p0+p1)/(l0+l1) + w1*(p2+p3)/(l2+l3) + w2*(p4..11)/(l4..11)
// ---------------------------------------------------------------------------
__global__ __launch_bounds__(256) void k_comb(
    const float* __restrict__ po, const float* __restrict__ lb,
    const float* __restrict__ attn_w, float* __restrict__ out)
{
    const int v = blockIdx.x*256 + threadIdx.x;      // f32x4 index over [B,S,D]
    const int qg = v >> 4;                           // global row b*S+q
    const float aw0 = attn_w[0], aw1 = attn_w[1], aw2 = attn_w[2];
    const float iws = fast_rcp(aw0 + aw1 + aw2);
    const f32x4* p = (const f32x4*)po;
    const int NQ = BB*SS;

    f32x4 s01 = p[(size_t)0*65536 + v] + p[(size_t)1*65536 + v];
    f32x4 s23 = p[(size_t)2*65536 + v] + p[(size_t)3*65536 + v];
    f32x4 s3s = {0,0,0,0};
    float l3 = 0.f;
    #pragma unroll
    for (int s = 4; s < 12; ++s) {
        s3s += p[(size_t)s*65536 + v];
        l3 += lb[s*NQ + qg];
    }
    const float f0 = aw0 * iws * fast_rcp(lb[0*NQ + qg] + lb[1*NQ + qg]);
    const float f1 = aw1 * iws * fast_rcp(lb[2*NQ + qg] + lb[3*NQ + qg]);
    const float f2 = aw2 * iws * fast_rcp(l3);
    f32x4 o;
    #pragma unroll
    for (int u = 0; u < 4; ++u)
        o[u] = __builtin_fmaf(s01[u], f0,
               __builtin_fmaf(s23[u], f1, s3s[u]*f2));
    ((f32x4*)out)[v] = o;
}

extern "C" void kernel_launch(void* const* d_in, const int* in_sizes, int n_in,
                              void* d_out, int out_size, void* d_ws, size_t ws_size,
                              hipStream_t stream) {
    (void)in_sizes; (void)n_in; (void)out_size; (void)ws_size;
    const float* x          = (const float*)d_in[0];
    const float* Wq         = (const float*)d_in[1];
    const float* Wk         = (const float*)d_in[2];
    const float* bk         = (const float*)d_in[3];
    const float* Wv         = (const float*)d_in[4];
    const float* attn_w     = (const float*)d_in[5];
    const float* attn_scale = (const float*)d_in[6];
    float* out              = (float*)d_out;

    // workspace carve-up (~17.5 MB)
    float* exf = (float*)d_ws;                            // [B,S,64] f32
    unsigned short* qh  = (unsigned short*)(exf + NSD);   // 6 bf16 [B,S,64]
    unsigned short* ql  = qh  + NSD;
    unsigned short* kh  = ql  + NSD;
    unsigned short* kl  = kh  + NSD;
    unsigned short* xh  = kl  + NSD;
    unsigned short* xlo = xh  + NSD;
    unsigned short* xT  = xlo + NSD;                      // bf16 [B,64,S]
    unsigned short* vT  = xT  + NSD;
    float* po = (float*)(vT + NSD);                       // [12][B,S,64] f32
    float* lb = po + (size_t)12*NSD;                      // [12][B*S]

    k_proj <<<1024, 256, 0, stream>>>(x, Wq, Wk, bk, Wv,
                                      qh, ql, kh, kl, xh, xlo, exf, xT, vT);
    k_fused<<<1536, 256, 0, stream>>>(xh, xlo, qh, ql, kh, kl, exf, xT, vT,
                                      attn_scale, po, lb);
    k_comb <<<256, 256, 0, stream>>>(po, lb, attn_w, out);
}

// Round 8
// 51.923 us; speedup vs baseline: 1.2882x; 1.2882x over previous
//
#include <hip/hip_runtime.h>
#include <hip/hip_bf16.h>

#define BB 4
#define SS 1024
#define NSD (BB*SS*64)

typedef __attribute__((ext_vector_type(4))) float f32x4;
typedef __attribute__((ext_vector_type(8))) short bf16x8;

__device__ __forceinline__ float fast_exp2(float x) { return __builtin_amdgcn_exp2f(x); }
__device__ __forceinline__ float fast_rcp(float x)  { return __builtin_amdgcn_rcpf(x); }

__device__ __forceinline__ unsigned short f2bf(float f) {
    unsigned int u = __builtin_bit_cast(unsigned int, f);
    u += 0x7fffu + ((u >> 16) & 1u);
    return (unsigned short)(u >> 16);
}
__device__ __forceinline__ float bf2f(unsigned short u) {
    unsigned int v = (unsigned int)u << 16;
    return __builtin_bit_cast(float, v);
}

// sum of 4 sigmoids 1/(1+eq_d*ek_d) with one reciprocal
__device__ __forceinline__ float sig4(const f32x4 eq, const f32x4 ek) {
    float A = __builtin_fmaf(eq[0], ek[0], 1.0f);
    float B = __builtin_fmaf(eq[1], ek[1], 1.0f);
    float C = __builtin_fmaf(eq[2], ek[2], 1.0f);
    float D = __builtin_fmaf(eq[3], ek[3], 1.0f);
    float AB = A*B, CD = C*D;
    float num = __builtin_fmaf(A+B, CD, (C+D)*AB);
    return num * fast_rcp(AB*CD);
}

// ---------------------------------------------------------------------------
// K1: projections + hi/lo bf16 splits (unchanged, verified rounds 4-7).
// ---------------------------------------------------------------------------
__global__ __launch_bounds__(256) void k_proj(
    const float* __restrict__ x, const float* __restrict__ Wq,
    const float* __restrict__ Wk, const float* __restrict__ bkv,
    const float* __restrict__ Wv,
    unsigned short* __restrict__ qh, unsigned short* __restrict__ ql,
    unsigned short* __restrict__ kh, unsigned short* __restrict__ kl,
    unsigned short* __restrict__ xh, unsigned short* __restrict__ xlo,
    float* __restrict__ exf,
    unsigned short* __restrict__ xT, unsigned short* __restrict__ vT)
{
    __shared__ float xsh[4*68];
    const int t = threadIdx.x;
    const int r = t & 3, cc = t >> 2;
    const int row0 = blockIdx.x * 4;
    if (t < 64) {
        const int rr = t >> 4, seg = (t & 15) * 4;
        *(f32x4*)(xsh + rr*68 + seg) =
            *(const f32x4*)(x + (size_t)(row0 + rr)*64 + seg);
    }
    __syncthreads();

    const float* wqp = Wq + cc*64;
    const float* wkp = Wk + cc*64;
    const float* wvp = Wv + cc*64;
    float aq = 0.f, ak = 0.f, av = 0.f;
    #pragma unroll 4
    for (int e0 = 0; e0 < 64; e0 += 4) {
        f32x4 xv = *(const f32x4*)(xsh + r*68 + e0);
        f32x4 q4 = *(const f32x4*)(wqp + e0);
        f32x4 k4 = *(const f32x4*)(wkp + e0);
        f32x4 v4 = *(const f32x4*)(wvp + e0);
        #pragma unroll
        for (int u = 0; u < 4; ++u) {
            aq = __builtin_fmaf(xv[u], q4[u], aq);
            ak = __builtin_fmaf(xv[u], k4[u], ak);
            av = __builtin_fmaf(xv[u], v4[u], av);
        }
    }
    const int row = row0 + r;
    const int b = row >> 10, srow = row & 1023;
    const float C2 = 2.8853900817779268f;   // 2*log2(e)
    ak += bkv[cc];
    const size_t idx = (size_t)row*64 + cc;
    unsigned short h;
    h = f2bf(aq); qh[idx] = h; ql[idx] = f2bf(aq - bf2f(h));
    h = f2bf(ak); kh[idx] = h; kl[idx] = f2bf(ak - bf2f(h));
    const float xv_ = xsh[r*68 + cc];
    h = f2bf(xv_); xh[idx] = h; xlo[idx] = f2bf(xv_ - bf2f(h));
    exf[idx] = fast_exp2(C2 * xv_);
    xT[((size_t)b*64 + cc)*1024 + srow] = h;
    vT[((size_t)b*64 + cc)*1024 + srow] = f2bf(av);
}

// ---------------------------------------------------------------------------
// K2: fused scores+softmax+PV.
//  bx < 576 : branch 3, LDS-staged, conflict-free swizzle, VALU-bound tile.
//    Block -> (b, band[32q], cg). Wave wv: chunk c=cg*4+wv (32 k-rows).
//    Lane: q-rows (l&7)+8i (i<4), k-cols (l>>3)+8j (j<4): Rq=4 x Rk=4.
//    eq/ek LDS with slot swizzle m^(row&7) -> all reads bank-balanced.
//    P via per-wave LDS (stride 40 u16, aligned) -> MFMA A-frags.
//    In-block 4-wave O-reduction via flat-swizzled reuse of ek buffer.
//    Slots 4+cg (k_comb masks cg >= ncg(band)).
//  bx >= 576 : branches 1,2 (split-bf16 MFMA scores; verified r6/r7). Slots 0..3.
// ---------------------------------------------------------------------------
__global__ __launch_bounds__(256, 3) void k_fused(
    const unsigned short* __restrict__ xh, const unsigned short* __restrict__ xlo,
    const unsigned short* __restrict__ qh, const unsigned short* __restrict__ ql,
    const unsigned short* __restrict__ kh, const unsigned short* __restrict__ kl,
    const float* __restrict__ exf,
    const unsigned short* __restrict__ xT, const unsigned short* __restrict__ vT,
    const float* __restrict__ attn_scale,
    float* __restrict__ po, float* __restrict__ lb)
{
    __shared__ float eqbuf[32*64];            // 8 KB, swizzled
    __shared__ float ekbuf[4][32*64];         // 32 KB, swizzled; reused as obuf
    __shared__ unsigned short Plb[4][32*40];  // 10 KB, P tiles (stride 80B)
    __shared__ float lpart[4][32];

    const int t = threadIdx.x;
    const int bx = blockIdx.x;
    const int lane = t & 63, wv = t >> 6;
    const int l7 = lane & 7, l8 = lane >> 3;
    const int l15 = lane & 15, g = lane >> 4;
    const float LOG2E = 1.4426950408889634f;

    if (bx < 576) {
        // ================= branch 3 =================
        const int b = bx / 144;
        int rr = bx % 144;
        int band = 31;
        while (rr >= ((band + 4) >> 2)) { rr -= (band + 4) >> 2; --band; }
        const int cg = rr;
        const int q0 = band * 32;
        const int c = cg * 4 + wv;
        const bool active = (c <= band);
        const int kc = c * 32;

        {   // stage eq (cooperative, swizzled): 512 b128 by 256 threads
            const float* src = exf + ((size_t)b*SS + q0) * 64;
            #pragma unroll
            for (int ii = 0; ii < 2; ++ii) {
                const int idx = t + 256*ii;
                const int r0 = idx >> 4, m0 = idx & 15;
                *(f32x4*)(eqbuf + r0*64 + ((m0 ^ (r0 & 7)) << 2)) =
                    *(const f32x4*)(src + r0*64 + m0*4);
            }
        }
        if (active) {   // stage own ek (per wave, swizzled)
            const float* srck = exf + ((size_t)b*SS + kc) * 64;
            #pragma unroll
            for (int ii = 0; ii < 8; ++ii) {
                const int idx = lane + 64*ii;
                const int r0 = idx >> 4, m0 = idx & 15;
                *(f32x4*)(ekbuf[wv] + r0*64 + ((m0 ^ (r0 & 7)) << 2)) =
                    *(const f32x4*)(srck + r0*64 + m0*4);
            }
        }
        __syncthreads();

        f32x4 acc[2][4];
        #pragma unroll
        for (int a_ = 0; a_ < 2; ++a_)
            #pragma unroll
            for (int b_ = 0; b_ < 4; ++b_)
                acc[a_][b_] = (f32x4){0.f,0.f,0.f,0.f};
        float lrow[4] = {0.f,0.f,0.f,0.f};

        if (active) {
            float ar[4][4] = {};
            const float* ekw = ekbuf[wv];
            #pragma unroll 2
            for (int m = 0; m < 16; ++m) {
                f32x4 eqv[4], ekv[4];
                #pragma unroll
                for (int i = 0; i < 4; ++i)
                    eqv[i] = *(const f32x4*)(eqbuf + (l7 + 8*i)*64 + ((m ^ l7) << 2));
                #pragma unroll
                for (int j = 0; j < 4; ++j)
                    ekv[j] = *(const f32x4*)(ekw + (l8 + 8*j)*64 + ((m ^ l8) << 2));
                #pragma unroll
                for (int i = 0; i < 4; ++i)
                    #pragma unroll
                    for (int j = 0; j < 4; ++j)
                        ar[i][j] += sig4(eqv[i], ekv[j]);
            }
            // exp (fixed shift -32), mask, P -> LDS, row sums
            unsigned short* Plw = Plb[wv];
            #pragma unroll
            for (int i = 0; i < 4; ++i) {
                const int q = q0 + l7 + 8*i;
                float lr = 0.f;
                #pragma unroll
                for (int j = 0; j < 4; ++j) {
                    const int kg = kc + l8 + 8*j;
                    float e = (kg <= q)
                        ? fast_exp2(__builtin_fmaf(ar[i][j], -2.8853900817779268f,
                                                   46.166241308446475f))
                        : 0.f;
                    lr += e;
                    Plw[(l7 + 8*i)*40 + l8 + 8*j] = f2bf(e);
                }
                lrow[i] = lr;
            }
            #pragma unroll
            for (int i = 0; i < 4; ++i) {
                lrow[i] += __shfl_xor(lrow[i], 8, 64);
                lrow[i] += __shfl_xor(lrow[i], 16, 64);
                lrow[i] += __shfl_xor(lrow[i], 32, 64);
            }
            // PV: A-frags from Plw, B-frags direct from xT (L2-hot)
            const unsigned short* vb = xT + (size_t)b*64*1024;
            #pragma unroll
            for (int qt2 = 0; qt2 < 2; ++qt2) {
                bf16x8 af = *(const bf16x8*)(Plw + (qt2*16 + l15)*40 + g*8);
                #pragma unroll
                for (int db = 0; db < 4; ++db) {
                    bf16x8 bf_ = *(const bf16x8*)(vb + (size_t)(db*16 + l15)*1024 + kc + g*8);
                    acc[qt2][db] = __builtin_amdgcn_mfma_f32_16x16x32_bf16(af, bf_, acc[qt2][db], 0, 0, 0);
                }
            }
        }

        // O partial -> obuf (= own ekbuf region), flat-swizzled for balanced reduce
        {
            float* obufw = ekbuf[wv];
            #pragma unroll
            for (int qt2 = 0; qt2 < 2; ++qt2)
                #pragma unroll
                for (int db = 0; db < 4; ++db)
                    #pragma unroll
                    for (int ii = 0; ii < 4; ++ii) {
                        const int row = qt2*16 + g*4 + ii;
                        const int col = db*16 + l15;
                        const int L = (row << 4) + (col >> 2);
                        const int P = L ^ ((L >> 3) & 7);
                        obufw[(P << 2) + (col & 3)] = acc[qt2][db][ii];
                    }
            if (lane < 8) {
                #pragma unroll
                for (int i = 0; i < 4; ++i) lpart[wv][lane + 8*i] = lrow[i];
            }
        }
        __syncthreads();

        // reduce 4 waves, write po/lb slot 4+cg
        {
            f32x4 s0 = {0,0,0,0}, s1 = {0,0,0,0};
            #pragma unroll
            for (int w = 0; w < 4; ++w) {
                const int L0 = t*2,     P0 = L0 ^ ((L0 >> 3) & 7);
                const int L1 = t*2 + 1, P1 = L1 ^ ((L1 >> 3) & 7);
                s0 += *(const f32x4*)(ekbuf[w] + (P0 << 2));
                s1 += *(const f32x4*)(ekbuf[w] + (P1 << 2));
            }
            float* pob = po + (size_t)(4+cg)*NSD
                       + ((size_t)b*SS + q0 + (t >> 3))*64 + (t & 7)*8;
            *(f32x4*)pob = s0;
            *(f32x4*)(pob + 4) = s1;
            if (t < 32) {
                float l = lpart[0][t] + lpart[1][t] + lpart[2][t] + lpart[3][t];
                lb[(size_t)(4+cg)*(BB*SS) + (size_t)b*SS + q0 + t] = l;
            }
        }
    } else {
        // ================= branches 1,2 (verified r6/r7 path) =============
        unsigned short* Pl = (unsigned short*)Plb;   // 16*72 u16 region
        const int y = bx - 576;
        const int split = y & 1, b = (y >> 1) & 3;
        const int qt = 63 - ((y >> 3) & 63);
        const int br = (y >> 9) & 1;
        const int q0 = qt * 16;
        const int nc = (qt >> 2) + 1;

        const unsigned short* Ah_p = (br ? qh : xh) + ((size_t)b*SS + q0)*64;
        const unsigned short* Al_p = (br ? ql : xlo) + ((size_t)b*SS + q0)*64;
        const unsigned short* Bh_p = (br ? kh : xh) + (size_t)b*SS*64;
        const unsigned short* Bl_p = (br ? kl : xlo) + (size_t)b*SS*64;
        const unsigned short* Vb   = (br ? vT : xT) + (size_t)b*64*1024;

        const int ko = g * 8;
        bf16x8 Ah0 = *(const bf16x8*)(Ah_p + (size_t)l15*64 + ko);
        bf16x8 Ah1 = *(const bf16x8*)(Ah_p + (size_t)l15*64 + 32 + ko);
        bf16x8 Al0 = *(const bf16x8*)(Al_p + (size_t)l15*64 + ko);
        bf16x8 Al1 = *(const bf16x8*)(Al_p + (size_t)l15*64 + 32 + ko);

        const float pscale = br ? (0.125f * attn_scale[0] * LOG2E) : LOG2E;
        const float pshift = br ? 0.f : (-64.f * LOG2E);

        f32x4 lacc = {0,0,0,0};
        f32x4 oacc = {0,0,0,0};

        for (int cc2 = split; cc2 < nc; cc2 += 2) {
            const int kc = cc2 * 64;
            const int krow = kc + wv*16 + l15;
            bf16x8 Bh0 = *(const bf16x8*)(Bh_p + (size_t)krow*64 + ko);
            bf16x8 Bh1 = *(const bf16x8*)(Bh_p + (size_t)krow*64 + 32 + ko);
            bf16x8 Bl0 = *(const bf16x8*)(Bl_p + (size_t)krow*64 + ko);
            bf16x8 Bl1 = *(const bf16x8*)(Bl_p + (size_t)krow*64 + 32 + ko);
            f32x4 s = {0,0,0,0};
            s = __builtin_amdgcn_mfma_f32_16x16x32_bf16(Ah0, Bh0, s, 0, 0, 0);
            s = __builtin_amdgcn_mfma_f32_16x16x32_bf16(Ah1, Bh1, s, 0, 0, 0);
            s = __builtin_amdgcn_mfma_f32_16x16x32_bf16(Ah0, Bl0, s, 0, 0, 0);
            s = __builtin_amdgcn_mfma_f32_16x16x32_bf16(Ah1, Bl1, s, 0, 0, 0);
            s = __builtin_amdgcn_mfma_f32_16x16x32_bf16(Al0, Bh0, s, 0, 0, 0);
            s = __builtin_amdgcn_mfma_f32_16x16x32_bf16(Al1, Bh1, s, 0, 0, 0);
            const int kg = kc + wv*16 + l15;
            #pragma unroll
            for (int i = 0; i < 4; ++i) {
                const int q = q0 + g*4 + i;
                float e = (kg <= q) ? fast_exp2(__builtin_fmaf(s[i], pscale, pshift)) : 0.f;
                lacc[i] += e;
                Pl[(g*4+i)*72 + wv*16 + l15] = f2bf(e);
            }
            __syncthreads();
            #pragma unroll
            for (int ks = 0; ks < 2; ++ks) {
                bf16x8 af = *(const bf16x8*)(Pl + l15*72 + ks*32 + g*8);
                bf16x8 bf_ = *(const bf16x8*)(Vb + (size_t)(wv*16 + l15)*1024 + kc + ks*32 + g*8);
                oacc = __builtin_amdgcn_mfma_f32_16x16x32_bf16(af, bf_, oacc, 0, 0, 0);
            }
            __syncthreads();
        }
        #pragma unroll
        for (int off = 8; off >= 1; off >>= 1) {
            lacc[0] += __shfl_xor(lacc[0], off, 64);
            lacc[1] += __shfl_xor(lacc[1], off, 64);
            lacc[2] += __shfl_xor(lacc[2], off, 64);
            lacc[3] += __shfl_xor(lacc[3], off, 64);
        }
        if (l15 == 0) {
            #pragma unroll
            for (int i = 0; i < 4; ++i) lpart[wv][g*4 + i] = lacc[i];
        }
        __syncthreads();
        const size_t slot = (size_t)(br*2 + split);
        if (t < 16) {
            float l = lpart[0][t] + lpart[1][t] + lpart[2][t] + lpart[3][t];
            lb[slot*((size_t)BB*SS) + (size_t)b*SS + q0 + t] = l;
        }
        float* pob = po + slot*((size_t)NSD) + ((size_t)b*SS + q0)*64;
        #pragma unroll
        for (int i = 0; i < 4; ++i)
            pob[(size_t)(g*4 + i)*64 + wv*16 + l15] = oacc[i];
    }
}

// ---------------------------------------------------------------------------
// K3: out = w0*(p0+p1)/(l0+l1) + w1*(p2+p3)/(l2+l3) + w2*(br3 slots < ncg)
// br3 slot count per row depends on its band: ncg = (band+4)>>2.
// ---------------------------------------------------------------------------
__global__ __launch_bounds__(256) void k_comb(
    const float* __restrict__ po, const float* __restrict__ lb,
    const float* __restrict__ attn_w, float* __restrict__ out)
{
    const int v = blockIdx.x*256 + threadIdx.x;      // f32x4 index over [B,S,D]
    const int qg = v >> 4;                           // global row b*S+q
    const int band = (qg & 1023) >> 5;
    const int ncg = (band + 4) >> 2;
    const float aw0 = attn_w[0], aw1 = attn_w[1], aw2 = attn_w[2];
    const float iws = fast_rcp(aw0 + aw1 + aw2);
    const f32x4* p = (const f32x4*)po;
    const int NQ = BB*SS;

    f32x4 s01 = p[(size_t)0*65536 + v] + p[(size_t)1*65536 + v];
    f32x4 s23 = p[(size_t)2*65536 + v] + p[(size_t)3*65536 + v];
    f32x4 s3s = {0,0,0,0};
    float l3 = 0.f;
    #pragma unroll
    for (int s = 0; s < 8; ++s) {
        if (s < ncg) {
            s3s += p[(size_t)(4+s)*65536 + v];
            l3 += lb[(4+s)*NQ + qg];
        }
    }
    const float f0 = aw0 * iws * fast_rcp(lb[0*NQ + qg] + lb[1*NQ + qg]);
    const float f1 = aw1 * iws * fast_rcp(lb[2*NQ + qg] + lb[3*NQ + qg]);
    const float f2 = aw2 * iws * fast_rcp(l3);
    f32x4 o;
    #pragma unroll
    for (int u = 0; u < 4; ++u)
        o[u] = __builtin_fmaf(s01[u], f0,
               __builtin_fmaf(s23[u], f1, s3s[u]*f2));
    ((f32x4*)out)[v] = o;
}

extern "C" void kernel_launch(void* const* d_in, const int* in_sizes, int n_in,
                              void* d_out, int out_size, void* d_ws, size_t ws_size,
                              hipStream_t stream) {
    (void)in_sizes; (void)n_in; (void)out_size; (void)ws_size;
    const float* x          = (const float*)d_in[0];
    const float* Wq         = (const float*)d_in[1];
    const float* Wk         = (const float*)d_in[2];
    const float* bk         = (const float*)d_in[3];
    const float* Wv         = (const float*)d_in[4];
    const float* attn_w     = (const float*)d_in[5];
    const float* attn_scale = (const float*)d_in[6];
    float* out              = (float*)d_out;

    // workspace carve-up (~17.5 MB)
    float* exf = (float*)d_ws;                            // [B,S,64] f32
    unsigned short* qh  = (unsigned short*)(exf + NSD);   // 6 bf16 [B,S,64]
    unsigned short* ql  = qh  + NSD;
    unsigned short* kh  = ql  + NSD;
    unsigned short* kl  = kh  + NSD;
    unsigned short* xh  = kl  + NSD;
    unsigned short* xlo = xh  + NSD;
    unsigned short* xT  = xlo + NSD;                      // bf16 [B,64,S]
    unsigned short* vT  = xT  + NSD;
    float* po = (float*)(vT + NSD);                       // [12][B,S,64] f32
    float* lb = po + (size_t)12*NSD;                      // [12][B*S]

    k_proj <<<1024, 256, 0, stream>>>(x, Wq, Wk, bk, Wv,
                                      qh, ql, kh, kl, xh, xlo, exf, xT, vT);
    k_fused<<<1600, 256, 0, stream>>>(xh, xlo, qh, ql, kh, kl, exf, xT, vT,
                                      attn_scale, po, lb);
    k_comb <<<256, 256, 0, stream>>>(po, lb, attn_w, out);
}